// Round 7
// baseline (359.544 us; speedup 1.0000x reference)
//
#include <hip/hip_runtime.h>

// TopK_36653250904599: x [16,256,128,128] f32 -> l2-normalize over HW=16384,
// top-16 values [B,C,16] + (h,w) coords [B,C,16,2] (coords stored as floats).
//
// R7: K1 is barrier-free and LDS-free. Each WAVE owns a contiguous 1024-elem
// chunk (16 chunks/row, 65536 chunks). Candidates (>T0=2.5, ~6.3/chunk for
// N(0,1)) are compacted via in-wave prefix scan (__shfl_up) into a 64-slot
// per-chunk global list -- no atomics, no LDS, no __syncthreads, no init.
// lane0 stores the chunk's sumsq partial, lane63 the (uncapped) count.
// K2 gathers 16 chunk lists per row, computes scale from the 16 partials in
// fixed order (deterministic), repacks with normalized fp32-rounded values,
// all-pairs ranks (idx-asc tiebreak == jax.lax.top_k). Fallback bisection
// row-rescan if any chunk overflowed or total outside [16,1024] (never fires
// for N(0,1)). R6's K1 still had 2 block barriers coupling wave progress ->
// ~2.9 TB/s; removing all intra-block coupling is the point of R7.

#define KSEL 16
#define HW    16384
#define WDIM  128
#define CHUNK 1024
#define CAPC  64                    // slots per chunk list
#define CAP   1024                  // = 16*CAPC, max per row
#define T0    2.5f
#define NROWS 4096
#define NCHUNK (NROWS * 16)         // 65536
#define NB1   (NCHUNK / 4)          // 16384 blocks, 4 waves each
#define VALS_TOTAL (NROWS * KSEL)   // 65536 value floats, then coords

typedef float floatx4 __attribute__((ext_vector_type(4)));

// ws layout: qsum f32[65536] @0 (256KB) | qcnt u32[65536] @256KB (256KB)
//            qcand u64[65536*64] @512KB (32MB)

__global__ __launch_bounds__(256) void k1_stream(const float* __restrict__ x,
                                                 float* __restrict__ qsum,
                                                 unsigned* __restrict__ qcnt,
                                                 unsigned long long* __restrict__ qcand) {
    const int t     = threadIdx.x;
    const int lane  = t & 63;
    const int chunk = blockIdx.x * 4 + (t >> 6);   // wave-private chunk

    const floatx4* p = (const floatx4*)(x + (size_t)chunk * CHUNK);

    floatx4 buf[4];
    #pragma unroll
    for (int k = 0; k < 4; ++k)
        buf[k] = __builtin_nontemporal_load(&p[k * 64 + lane]);

    float sumsq = 0.0f;
    unsigned msk = 0;
    #pragma unroll
    for (int k = 0; k < 4; ++k) {
        sumsq = fmaf(buf[k].x, buf[k].x, sumsq);
        sumsq = fmaf(buf[k].y, buf[k].y, sumsq);
        sumsq = fmaf(buf[k].z, buf[k].z, sumsq);
        sumsq = fmaf(buf[k].w, buf[k].w, sumsq);
        msk |= (buf[k].x > T0) ? (1u << (4 * k + 0)) : 0u;
        msk |= (buf[k].y > T0) ? (1u << (4 * k + 1)) : 0u;
        msk |= (buf[k].z > T0) ? (1u << (4 * k + 2)) : 0u;
        msk |= (buf[k].w > T0) ? (1u << (4 * k + 3)) : 0u;
    }

    // in-wave inclusive prefix scan of per-lane candidate counts
    unsigned cnum = (unsigned)__popc(msk);
    unsigned inc = cnum;
    #pragma unroll
    for (int off = 1; off < 64; off <<= 1) {
        unsigned u = (unsigned)__shfl_up((int)inc, off, 64);
        if (lane >= off) inc += u;
    }
    unsigned slot = inc - cnum;      // exclusive prefix

    if (msk) {
        const size_t basep = (size_t)chunk * CAPC;
        const int inrow_base = (chunk & 15) * CHUNK;
        #pragma unroll
        for (int k = 0; k < 4; ++k) {
            #pragma unroll
            for (int c = 0; c < 4; ++c) {
                float v = (c == 0) ? buf[k].x : (c == 1) ? buf[k].y
                        : (c == 2) ? buf[k].z : buf[k].w;
                if (v > T0) {
                    if (slot < CAPC) {
                        unsigned u  = __float_as_uint(v);
                        unsigned mm = u ^ (((unsigned)((int)u >> 31)) | 0x80000000u);
                        int idx = inrow_base + (k * 64 + lane) * 4 + c;
                        qcand[basep + slot] = ((unsigned long long)mm << 32) |
                                              (unsigned)(16383 - idx);
                    }
                    slot++;
                }
            }
        }
    }

    #pragma unroll
    for (int off = 32; off > 0; off >>= 1)
        sumsq += __shfl_down(sumsq, off, 64);
    if (lane == 0)  qsum[chunk] = sumsq;
    if (lane == 63) qcnt[chunk] = inc;   // uncapped total for this chunk
}

__global__ __launch_bounds__(256) void k2_select(const float* __restrict__ x,
                                                 const float* __restrict__ qsum,
                                                 const unsigned* __restrict__ qcnt,
                                                 const unsigned long long* __restrict__ qcand,
                                                 float* __restrict__ out) {
    const int row = blockIdx.x;
    const int t   = threadIdx.x;

    __shared__ unsigned long long s_cand[CAP];
    __shared__ unsigned s_qc[16];
    __shared__ float s_qs[16];
    __shared__ unsigned s_cnt;

    if (t < 16) {
        s_qc[t] = qcnt[row * 16 + t];
        s_qs[t] = qsum[row * 16 + t];
    }
    __syncthreads();

    // every thread: fixed-order scale (deterministic) + offsets + overflow
    float tot = 0.0f;
    unsigned cnum = 0;
    bool ovf = false;
    unsigned offs[16];
    #pragma unroll
    for (int i = 0; i < 16; ++i) {
        offs[i] = cnum;
        unsigned c = s_qc[i];
        ovf |= (c > CAPC);
        cnum += c;
        tot += s_qs[i];
    }
    const float scale = 1.0f / sqrtf(fmaxf(tot, 1e-12f));

    unsigned cnt;
    if (!ovf && cnum >= KSEL) {      // cnum <= 16*64 = CAP always here
        #pragma unroll
        for (int q = 0; q < 16; ++q)
            for (unsigned i = t; i < s_qc[q]; i += 256)
                s_cand[offs[q] + i] = qcand[(size_t)(row * 16 + q) * CAPC + i];
        cnt = cnum;
        __syncthreads();
    } else {
        // slow path (never for N(0,1)): bisect T, re-reading the row
        const float* xr = x + (size_t)row * HW;
        float T = T0, lo = -3.0e38f, hi = 3.0e38f;
        cnt = 0;
        for (int it = 0; it < 32; ++it) {
            __syncthreads();
            if (t == 0) s_cnt = 0;
            __syncthreads();
            for (int i = t; i < HW; i += 256) {
                float v = xr[i];
                if (v > T) {
                    unsigned slot = atomicAdd(&s_cnt, 1u);
                    if (slot < CAP) {
                        unsigned u  = __float_as_uint(v);
                        unsigned mm = u ^ (((unsigned)((int)u >> 31)) | 0x80000000u);
                        s_cand[slot] = ((unsigned long long)mm << 32) |
                                       (unsigned)(16383 - i);
                    }
                }
            }
            __syncthreads();
            cnt = s_cnt;
            if (cnt >= KSEL && cnt <= CAP) break;
            if (cnt < KSEL) { hi = T; T = (lo < -1.0e38f) ? T - 1.0f : 0.5f * (lo + T); }
            else            { lo = T; T = (hi >  1.0e38f) ? T + 1.0f : 0.5f * (T + hi); }
        }
        if (cnt > CAP) cnt = CAP;
    }

    // repack with normalized fp32-rounded value (rounding ties -> idx-asc
    // tiebreak in low bits matches jax.lax.top_k)
    for (unsigned i = t; i < cnt; i += 256) {
        unsigned long long p = s_cand[i];
        unsigned m = (unsigned)(p >> 32);
        unsigned u = (m & 0x80000000u) ? (m ^ 0x80000000u) : ~m;
        float vn = __uint_as_float(u) * scale;
        unsigned u2 = __float_as_uint(vn);
        unsigned m2 = u2 ^ (((unsigned)((int)u2 >> 31)) | 0x80000000u);
        s_cand[i] = ((unsigned long long)m2 << 32) | (p & 0xFFFFFFFFull);
    }
    __syncthreads();

    // all-pairs rank (ranks unique via idx tiebreak) + write
    for (unsigned i = t; i < cnt; i += 256) {
        unsigned long long p = s_cand[i];
        int rank = 0;
        for (unsigned j = 0; j < cnt; ++j) rank += (s_cand[j] > p) ? 1 : 0;
        if (rank < KSEL) {
            unsigned m = (unsigned)(p >> 32);
            unsigned u = (m & 0x80000000u) ? (m ^ 0x80000000u) : ~m;
            float vn = __uint_as_float(u);
            int idx = 16383 - (int)(unsigned)(p & 0xFFFFFFFFull);
            out[row * KSEL + rank] = vn;
            float* coor = out + VALS_TOTAL + ((size_t)row * KSEL + rank) * 2;
            coor[0] = (float)(idx >> 7);          // h
            coor[1] = (float)(idx & (WDIM - 1));  // w
        }
    }
}

extern "C" void kernel_launch(void* const* d_in, const int* in_sizes, int n_in,
                              void* d_out, int out_size, void* d_ws, size_t ws_size,
                              hipStream_t stream) {
    const float* x = (const float*)d_in[0];
    float* out = (float*)d_out;
    char* ws = (char*)d_ws;
    float* qsum = (float*)ws;                                   // 256 KB
    unsigned* qcnt = (unsigned*)(ws + 256 * 1024);              // 256 KB
    unsigned long long* qcand =
        (unsigned long long*)(ws + 512 * 1024);                 // 32 MB

    k1_stream<<<NB1, 256, 0, stream>>>(x, qsum, qcnt, qcand);
    k2_select<<<NROWS, 256, 0, stream>>>(x, qsum, qcnt, qcand, out);
}